// Round 16
// baseline (289.119 us; speedup 1.0000x reference)
//
#include <hip/hip_runtime.h>
#include <cstdint>
#include <cstddef>
#include <cmath>

typedef __attribute__((ext_vector_type(4))) float f32x4;
typedef __attribute__((ext_vector_type(8))) short bf16x8;

typedef const __attribute__((address_space(1))) void* gas_ptr;
typedef __attribute__((address_space(3))) void* las_ptr;

// compiler-native bf16 convert (RNE) -> v_cvt_pk_bf16_f32 path
static __device__ __forceinline__ short f2bf(float f) {
    __bf16 h = (__bf16)f;
    return __builtin_bit_cast(short, h);
}

constexpr int MP = 25088;   // 64 * 392 batch-padded rows (logical)

// ---------------- weights fp32 -> bf16 (x is converted inside the QKV GEMM) --
__global__ void cvt_w(const float* __restrict__ qw, const float* __restrict__ pw,
                      short* __restrict__ qwb, short* __restrict__ pwb)
{
    constexpr int NQ = 2304 * 768 / 4;
    constexpr int NP = 768 * 768 / 4;
    constexpr int NT = NQ + NP;
    int i = blockIdx.x * blockDim.x + threadIdx.x;
    const int stride = gridDim.x * blockDim.x;
    for (; i < NT; i += stride) {
        if (i < NQ) {
            const float4 v = reinterpret_cast<const float4*>(qw)[i];
            short4 o;
            o.x = f2bf(v.x); o.y = f2bf(v.y); o.z = f2bf(v.z); o.w = f2bf(v.w);
            reinterpret_cast<short4*>(qwb)[i] = o;
        } else {
            const int j = i - NQ;
            const float4 v = reinterpret_cast<const float4*>(pw)[j];
            short4 o;
            o.x = f2bf(v.x); o.y = f2bf(v.y); o.z = f2bf(v.z); o.w = f2bf(v.w);
            reinterpret_cast<short4*>(pwb)[j] = o;
        }
    }
}

// ---------------- QKV GEMM: A = x fp32 reg-staged+converted, B = bf16 DMA ---
// r14 engine geometry (128x128, BK=64, 4 waves, 64KB dbuf LDS, counted-vmcnt,
// XCD-bijective + G=14 supertile). A-path: fp32 x read direct (row-clamped
// for batch pad), cvt in-register, swizzled ds_write into the same LDS image
// the DMA path produced. Saves the standalone x-convert pass (~20 us HBM).
// Issue order per iter: A-loads FIRST, then B-DMA -> compiler's dependency
// waits retire A (oldest) without draining B; end-of-iter vmcnt(0) drains
// only the 4 B-DMAs issued a full compute-phase earlier.
__global__ __launch_bounds__(256) void gemm_qkv(
    const float* __restrict__ X, const short* __restrict__ Bw,
    const float* __restrict__ bias,
    short* __restrict__ qk, short* __restrict__ vT)
{
    constexpr int K = 768;
    constexpr int KT = 12;
    __shared__ __align__(16) short ldsraw[2 * 128 * 64 * 2];
    short* ldsA = ldsraw;
    short* ldsB = ldsraw + 2 * 128 * 64;

    const int tid  = threadIdx.x;
    const int lane = tid & 63;
    const int wid  = tid >> 6;
    const int lrow = lane & 15;
    const int lgrp = lane >> 4;
    const int wr   = wid >> 1;
    const int wc   = wid & 1;

    const int nwg = gridDim.x;
    const int q8  = nwg >> 3, r8 = nwg & 7;
    const int xcd = blockIdx.x & 7, bidx = blockIdx.x >> 3;
    const int wgid = (xcd < r8 ? xcd * (q8 + 1) : r8 * (q8 + 1) + (xcd - r8) * q8) + bidx;

    constexpr int G = 14, SG = G * 18;
    const int mg = wgid / SG;
    const int r_ = wgid - mg * SG;
    const int n_ = r_ / G;
    const int mi = r_ - n_ * G;
    const int m0 = (mg * G + mi) * 128;
    const int n0 = n_ * 128;

    f32x4 acc[4][4];
    #pragma unroll
    for (int i = 0; i < 4; ++i)
        #pragma unroll
        for (int j = 0; j < 4; ++j)
            acc[i][j] = f32x4{0.f, 0.f, 0.f, 0.f};

    // per-thread A chunks (kt-independent): chunk c = it*256+tid holds
    // bf16 elems [kcol, kcol+8) of tile-row (c>>3), at LDS byte c*16.
    const float* abase[4];
    #pragma unroll
    for (int it = 0; it < 4; ++it) {
        const int c   = it * 256 + tid;
        const int row = c >> 3;
        const int scb = ((c & 7) * 16) ^ ((row & 7) << 4);   // inverse swizzle
        const int kcol = scb >> 1;
        const int mp = m0 + row;
        const int b  = mp / 392;
        int nn = mp - b * 392; if (nn > 387) nn = 387;        // pad rows: clamp (values never used)
        abase[it] = X + (size_t)(b * 388 + nn) * 768 + kcol;
    }

    float4 ar[4][2];
    auto loadA = [&](int kt) {
        #pragma unroll
        for (int it = 0; it < 4; ++it) {
            ar[it][0] = *reinterpret_cast<const float4*>(abase[it] + kt * 64);
            ar[it][1] = *reinterpret_cast<const float4*>(abase[it] + kt * 64 + 4);
        }
    };
    auto writeA = [&](int buf) {
        #pragma unroll
        for (int it = 0; it < 4; ++it) {
            const int c = it * 256 + tid;
            bf16x8 v;
            v[0] = f2bf(ar[it][0].x); v[1] = f2bf(ar[it][0].y);
            v[2] = f2bf(ar[it][0].z); v[3] = f2bf(ar[it][0].w);
            v[4] = f2bf(ar[it][1].x); v[5] = f2bf(ar[it][1].y);
            v[6] = f2bf(ar[it][1].z); v[7] = f2bf(ar[it][1].w);
            *reinterpret_cast<bf16x8*>((char*)(ldsA + buf * 128 * 64) + c * 16) = v;
        }
    };
    auto stageB = [&](int kt, int buf) {
        #pragma unroll
        for (int it = 0; it < 4; ++it) {
            const int c   = it * 256 + wid * 64 + lane;
            const int row = c >> 3;
            const int scb = ((c & 7) * 16) ^ ((row & 7) << 4);
            const short* gb = Bw + (size_t)(n0 + row) * K + kt * 64 + (scb >> 1);
            __builtin_amdgcn_global_load_lds((gas_ptr)gb, (las_ptr)((char*)(ldsB + buf * 128 * 64) + c * 16), 16, 0, 0);
        }
    };

    // prologue: tile 0
    loadA(0);
    stageB(0, 0);
    writeA(0);                                        // compiler waits the A-loads
    asm volatile("s_waitcnt vmcnt(0)" ::: "memory");  // B(0) landed
    asm volatile("s_waitcnt lgkmcnt(0)" ::: "memory");
    __builtin_amdgcn_s_barrier();

    for (int kt = 0; kt < KT; ++kt) {
        const int cur = kt & 1;
        const bool more = (kt + 1 < KT);
        if (more) {
            loadA(kt + 1);            // A first (oldest in vmcnt FIFO)
            stageB(kt + 1, cur ^ 1);  // then B-DMA
        }

        #pragma unroll
        for (int ks = 0; ks < 2; ++ks) {
            bf16x8 af[4], bfv[4];
            #pragma unroll
            for (int i = 0; i < 4; ++i) {
                const int r   = wr * 64 + i * 16 + lrow;
                const int byt = r * 128 + ((ks * 64 + lgrp * 16) ^ ((r & 7) << 4));
                af[i] = *reinterpret_cast<const bf16x8*>((const char*)(ldsA + cur * 128 * 64) + byt);
            }
            #pragma unroll
            for (int j = 0; j < 4; ++j) {
                const int r   = wc * 64 + j * 16 + lrow;
                const int byt = r * 128 + ((ks * 64 + lgrp * 16) ^ ((r & 7) << 4));
                bfv[j] = *reinterpret_cast<const bf16x8*>((const char*)(ldsB + cur * 128 * 64) + byt);
            }
            #pragma unroll
            for (int i = 0; i < 4; ++i)
                #pragma unroll
                for (int j = 0; j < 4; ++j)
                    acc[i][j] = __builtin_amdgcn_mfma_f32_16x16x32_bf16(af[i], bfv[j], acc[i][j], 0, 0, 0);
        }

        if (more) writeA(cur ^ 1);    // into the buffer last read before prev barrier (WAR-safe)

        __builtin_amdgcn_sched_barrier(0);
        asm volatile("s_waitcnt vmcnt(0)" ::: "memory");    // B(kt+1) landed (issued ~compute ago)
        asm volatile("s_waitcnt lgkmcnt(0)" ::: "memory");  // A-writes visible
        __builtin_amdgcn_s_barrier();
    }

    // ---------------- epilogue (r14-identical) ----------------
    const int mb = m0 + wr * 64;
    const int nb = n0 + wc * 64;
    if (n0 < 1536) {
        #pragma unroll
        for (int j = 0; j < 4; ++j) {
            const int c  = nb + j * 16 + lrow;
            const float sc = (c < 768) ? 0.18033688011116f : 1.0f;  // 0.125*log2(e) on q
            const float bv = bias[c];
            #pragma unroll
            for (int i = 0; i < 4; ++i) {
                #pragma unroll
                for (int r = 0; r < 4; ++r) {
                    const int m = mb + i * 16 + lgrp * 4 + r;
                    qk[(size_t)m * 1536 + c] = f2bf((acc[i][j][r] + bv) * sc);
                }
            }
        }
    } else {
        const int h = (nb - 1536) >> 6;
        short* lw = ldsraw + wid * (64 * 80);
        #pragma unroll
        for (int j = 0; j < 4; ++j) {
            const int dloc = j * 16 + lrow;
            const float bv = bias[nb + j * 16 + lrow];
            #pragma unroll
            for (int i = 0; i < 4; ++i)
                #pragma unroll
                for (int r = 0; r < 4; ++r)
                    lw[dloc * 80 + i * 16 + lgrp * 4 + r] = f2bf(acc[i][j][r] + bv);
        }
        asm volatile("s_waitcnt lgkmcnt(0)" ::: "memory");
        __builtin_amdgcn_sched_barrier(0);
        #pragma unroll
        for (int w = 0; w < 8; ++w) {
            const int d    = w * 8 + (lane >> 3);
            const int nloc = (lane & 7) * 8;
            const bf16x8 val = *reinterpret_cast<const bf16x8*>(lw + d * 80 + nloc);
            const int mchunk = mb + nloc;
            const int b  = mchunk / 392;
            const int nn = mchunk - b * 392;
            short* dst = vT + ((size_t)(b * 12 + h) * 64 + d) * 392 + nn;
            *reinterpret_cast<bf16x8*>(dst) = val;
        }
    }
}

// ---------------- proj GEMM (r14 engine, MODE-1 path, bf16 A) ----------------
__global__ __launch_bounds__(256) void gemm_proj(
    const short* __restrict__ A, const short* __restrict__ Bw,
    const float* __restrict__ bias, float* __restrict__ fo, int NB)
{
    constexpr int K = 768;
    constexpr int KT = 12;
    __shared__ __align__(16) short ldsraw[2 * 128 * 64 * 2];
    short* ldsA = ldsraw;
    short* ldsB = ldsraw + 2 * 128 * 64;

    const int tid  = threadIdx.x;
    const int lane = tid & 63;
    const int wid  = tid >> 6;
    const int lrow = lane & 15;
    const int lgrp = lane >> 4;
    const int wr   = wid >> 1;
    const int wc   = wid & 1;

    const int nwg = gridDim.x;
    const int q8  = nwg >> 3, r8 = nwg & 7;
    const int xcd = blockIdx.x & 7, bidx = blockIdx.x >> 3;
    const int wgid = (xcd < r8 ? xcd * (q8 + 1) : r8 * (q8 + 1) + (xcd - r8) * q8) + bidx;
    const int m0 = (wgid / NB) * 128;
    const int n0 = (wgid % NB) * 128;

    f32x4 acc[4][4];
    #pragma unroll
    for (int i = 0; i < 4; ++i)
        #pragma unroll
        for (int j = 0; j < 4; ++j)
            acc[i][j] = f32x4{0.f, 0.f, 0.f, 0.f};

    auto stage = [&](int kt, int buf) {
        #pragma unroll
        for (int it = 0; it < 4; ++it) {
            const int c   = it * 256 + wid * 64 + lane;
            const int row = c >> 3;
            const int scb = ((c & 7) * 16) ^ ((row & 7) << 4);
            const short* ga = A  + (size_t)(m0 + row) * K + kt * 64 + (scb >> 1);
            const short* gb = Bw + (size_t)(n0 + row) * K + kt * 64 + (scb >> 1);
            __builtin_amdgcn_global_load_lds((gas_ptr)ga, (las_ptr)((char*)(ldsA + buf * 128 * 64) + c * 16), 16, 0, 0);
            __builtin_amdgcn_global_load_lds((gas_ptr)gb, (las_ptr)((char*)(ldsB + buf * 128 * 64) + c * 16), 16, 0, 0);
        }
    };

    stage(0, 0);

    for (int kt = 0; kt < KT; ++kt) {
        const int cur = kt & 1;
        if (kt + 1 < KT) {
            stage(kt + 1, cur ^ 1);
            asm volatile("s_waitcnt vmcnt(8)" ::: "memory");
        } else {
            asm volatile("s_waitcnt vmcnt(0)" ::: "memory");
        }
        __builtin_amdgcn_s_barrier();
        __builtin_amdgcn_sched_barrier(0);

        #pragma unroll
        for (int ks = 0; ks < 2; ++ks) {
            bf16x8 af[4], bfv[4];
            #pragma unroll
            for (int i = 0; i < 4; ++i) {
                const int r   = wr * 64 + i * 16 + lrow;
                const int byt = r * 128 + ((ks * 64 + lgrp * 16) ^ ((r & 7) << 4));
                af[i] = *reinterpret_cast<const bf16x8*>((const char*)(ldsA + cur * 128 * 64) + byt);
            }
            #pragma unroll
            for (int j = 0; j < 4; ++j) {
                const int r   = wc * 64 + j * 16 + lrow;
                const int byt = r * 128 + ((ks * 64 + lgrp * 16) ^ ((r & 7) << 4));
                bfv[j] = *reinterpret_cast<const bf16x8*>((const char*)(ldsB + cur * 128 * 64) + byt);
            }
            #pragma unroll
            for (int i = 0; i < 4; ++i)
                #pragma unroll
                for (int j = 0; j < 4; ++j)
                    acc[i][j] = __builtin_amdgcn_mfma_f32_16x16x32_bf16(af[i], bfv[j], acc[i][j], 0, 0, 0);
        }

        __builtin_amdgcn_sched_barrier(0);
        __builtin_amdgcn_s_barrier();
    }

    const int mb = m0 + wr * 64;
    const int nb = n0 + wc * 64;
    #pragma unroll
    for (int i = 0; i < 4; ++i) {
        #pragma unroll
        for (int r = 0; r < 4; ++r) {
            const int m = mb + i * 16 + lgrp * 4 + r;
            #pragma unroll
            for (int j = 0; j < 4; ++j) {
                const int c = nb + j * 16 + lrow;
                fo[(size_t)m * 768 + c] = acc[i][j][r] + bias[c];
            }
        }
    }
}

// ---------------- flash attention (unchanged from round 14) ----------------
constexpr int PSTRB = 128;   // P row stride BYTES (64 keys)

static __device__ __forceinline__ void attn_chunk64(
    int kbeg, int k_len,
    const short* __restrict__ klds, const short* __restrict__ vlds,
    const bf16x8 (&qf)[2], char* __restrict__ my,
    int lrow, int lgrp,
    float& rs, f32x4 (&oacc)[4])
{
    f32x4 sacc[4];
    #pragma unroll
    for (int t = 0; t < 4; ++t) sacc[t] = f32x4{0.f, 0.f, 0.f, 0.f};

    #pragma unroll
    for (int t = 0; t < 4; ++t) {
        const int kl   = t * 16 + lrow;
        const int byt0 = kl * 128 + ((lgrp * 16) ^ ((kl & 7) << 4));
        const int byt1 = kl * 128 + ((64 + lgrp * 16) ^ ((kl & 7) << 4));
        const bf16x8 k0 = *reinterpret_cast<const bf16x8*>((const char*)klds + byt0);
        const bf16x8 k1 = *reinterpret_cast<const bf16x8*>((const char*)klds + byt1);
        // SWAPPED: A = K rows (keys), B = Q rows (q)
        sacc[t] = __builtin_amdgcn_mfma_f32_16x16x32_bf16(k0, qf[0], sacc[t], 0, 0, 0);
        sacc[t] = __builtin_amdgcn_mfma_f32_16x16x32_bf16(k1, qf[1], sacc[t], 0, 0, 0);
    }

    if (kbeg + 64 <= k_len) {          // uniform fast path: no key masking
        #pragma unroll
        for (int t = 0; t < 4; ++t) {
            short4 pk;
            #pragma unroll
            for (int r = 0; r < 4; ++r) {
                const float p = exp2f(sacc[t][r]);
                rs += p;
                ((short*)&pk)[r] = f2bf(p);
            }
            const int byt = lrow * PSTRB + ((t * 32 + lgrp * 8) ^ ((lrow & 7) << 4));
            *reinterpret_cast<short4*>(my + byt) = pk;
        }
    } else {
        #pragma unroll
        for (int t = 0; t < 4; ++t) {
            short4 pk;
            #pragma unroll
            for (int r = 0; r < 4; ++r) {
                const int key = kbeg + t * 16 + lgrp * 4 + r;   // row-indexed
                const float p = (key < k_len) ? exp2f(sacc[t][r]) : 0.f;
                rs += p;
                ((short*)&pk)[r] = f2bf(p);
            }
            const int byt = lrow * PSTRB + ((t * 32 + lgrp * 8) ^ ((lrow & 7) << 4));
            *reinterpret_cast<short4*>(my + byt) = pk;
        }
    }

    #pragma unroll
    for (int ks = 0; ks < 2; ++ks) {
        const bf16x8 pf = *reinterpret_cast<const bf16x8*>(
            my + lrow * PSTRB + ((ks * 64 + lgrp * 16) ^ ((lrow & 7) << 4)));
        #pragma unroll
        for (int dt = 0; dt < 4; ++dt) {
            const int d = dt * 16 + lrow;
            const bf16x8 vf = *reinterpret_cast<const bf16x8*>(
                (const char*)vlds + d * 128 + ((ks * 64 + lgrp * 16) ^ ((d & 7) << 4)));
            oacc[dt] = __builtin_amdgcn_mfma_f32_16x16x32_bf16(pf, vf, oacc[dt], 0, 0, 0);
        }
    }
}

// grid 5376 1-D; temporal-L2 map: 7 q-tiles of one bh consecutive on one XCD.
__global__ __launch_bounds__(256, 4) void attn_flash(
    const short* __restrict__ qkb, const short* __restrict__ vT,
    short* __restrict__ ao)
{
    __shared__ __align__(16) short klds[2][64 * 64];    // 16KB dbuf, swizzled
    __shared__ __align__(16) short vlds[2][64 * 64];    // 16KB dbuf, swizzled
    __shared__ __align__(16) char  plds[4][16 * PSTRB]; // 8KB, swizzled

    const int tid  = threadIdx.x;
    const int lane = tid & 63;
    const int wid  = tid >> 6;
    const int lrow = lane & 15;
    const int lgrp = lane >> 4;

    const int blk = blockIdx.x;
    const int xcd = blk & 7;
    const int i7  = blk >> 3;
    const int bh  = xcd * 96 + i7 / 7;
    const int bx  = i7 % 7;

    int q_start, qend, k_len, nch;
    if (bx < 2) { q_start = bx * 64;             qend = 128; k_len = 128; nch = 2; }
    else        { q_start = 128 + (bx - 2) * 64; qend = 388; k_len = 388; nch = 7; }

    const int q0 = q_start + wid * 16;

    const int b = bh / 12, h = bh - b * 12;
    const short* qbase = qkb + (size_t)b * 392 * 1536 + h * 64;
    const short* kbase = qbase + 768;
    const short* vbase = vT + (size_t)bh * 64 * 392;

    int qrow = q0 + lrow; if (qrow >= qend) qrow = qend - 1;
    bf16x8 qf[2];
    #pragma unroll
    for (int ks = 0; ks < 2; ++ks)
        qf[ks] = *reinterpret_cast<const bf16x8*>(qbase + (size_t)qrow * 1536 + ks * 32 + lgrp * 8);

    float rs = 0.f;
    f32x4 oacc[4];
    #pragma unroll
    for (int dt = 0; dt < 4; ++dt) oacc[dt] = f32x4{0.f, 0.f, 0.f, 0.f};

    char* my = &plds[wid][0];

    auto stage64 = [&](int ch, int buf) {
        const int kbeg = ch * 64;
        #pragma unroll
        for (int it = 0; it < 2; ++it) {
            const int c = it * 256 + tid;            // 0..511
            const int krow = c >> 3;                 // 0..63
            const int scb = ((c & 7) * 16) ^ ((krow & 7) << 4);
            int g = kbeg + krow; if (g > 391) g = 391;   // clamp into batch pad (masked)
            const short* gk = kbase + (size_t)g * 1536 + (scb >> 1);
            __builtin_amdgcn_global_load_lds((gas_ptr)gk, (las_ptr)((char*)&klds[buf][0] + c * 16), 16, 0, 0);
        }
        #pragma unroll
        for (int it = 0; it < 2; ++it) {
            const int c = it * 256 + tid;
            const int vrow = c >> 3;                 // d 0..63
            const int scb = ((c & 7) * 16) ^ ((vrow & 7) << 4);
            const short* gv = vbase + (size_t)vrow * 392 + kbeg + (scb >> 1);  // over-read finite, P==0
            __builtin_amdgcn_global_load_lds((gas_ptr)gv, (las_ptr)((char*)&vlds[buf][0] + c * 16), 16, 0, 0);
        }
    };

    stage64(0, 0);

    for (int ch = 0; ch < nch; ++ch) {
        const int cur = ch & 1;
        if (ch + 1 < nch) {
            stage64(ch + 1, cur ^ 1);                      // next chunk under compute
            asm volatile("s_waitcnt vmcnt(4)" ::: "memory");   // chunk ch landed
        } else {
            asm volatile("s_waitcnt vmcnt(0)" ::: "memory");
        }
        __builtin_amdgcn_s_barrier();
        __builtin_amdgcn_sched_barrier(0);

        attn_chunk64(ch * 64, k_len, &klds[cur][0], &vlds[cur][0],
                     qf, my, lrow, lgrp, rs, oacc);

        __builtin_amdgcn_sched_barrier(0);
        __builtin_amdgcn_s_barrier();   // all reads done before next stage overwrites
    }

    // row-sum lives per-lane for q = lane&15: reduce over the 4 lane-groups
    rs += __shfl_xor(rs, 16, 64);
    rs += __shfl_xor(rs, 32, 64);

    // redistribute: output rows are q = lgrp*4 + r; lanes 0..15 hold rs[q=lane]
    float inv[4];
    #pragma unroll
    for (int r = 0; r < 4; ++r) inv[r] = 1.0f / __shfl(rs, lgrp * 4 + r, 64);

    #pragma unroll
    for (int r = 0; r < 4; ++r) {
        const int qn = q0 + lgrp * 4 + r;
        if (qn < qend) {
            #pragma unroll
            for (int dt = 0; dt < 4; ++dt)
                ao[((size_t)b * 388 + qn) * 768 + h * 64 + dt * 16 + lrow] =
                    f2bf(oacc[dt][r] * inv[r]);
        }
    }
}

extern "C" void kernel_launch(void* const* d_in, const int* in_sizes, int n_in,
                              void* d_out, int out_size, void* d_ws, size_t ws_size,
                              hipStream_t stream) {
    (void)in_sizes; (void)n_in; (void)out_size; (void)ws_size;
    const float* x      = (const float*)d_in[0];
    const float* qkv_w  = (const float*)d_in[1];
    const float* qkv_b  = (const float*)d_in[2];
    const float* proj_w = (const float*)d_in[3];
    const float* proj_b = (const float*)d_in[4];
    float* out = (float*)d_out;

    char* ws = (char*)d_ws;
    short* attn = (short*)(ws);                       // [24832][768] bf16 attn-out
    short* qkb  = (short*)(ws + 38535168);            // [25088][1536] bf16 (q|k)
    short* vTb  = (short*)(ws + 115605504);           // [768][64][392] bf16
    short* qwb  = (short*)(ws + 154140672);           // 2304x768 bf16 (V tail over-reads land here)
    short* pwb  = (short*)(ws + 157679616);           // 768x768 bf16

    cvt_w<<<1024, 256, 0, stream>>>(qkv_w, proj_w, qwb, pwb);

    // QKV GEMM: A = x fp32 (fused convert), M'=25088 (196x128), N=2304 (18x128)
    gemm_qkv<<<dim3(196 * 18), 256, 0, stream>>>(x, qwb, qkv_b, qkb, vTb);

    attn_flash<<<dim3(5376), 256, 0, stream>>>(qkb, vTb, attn);

    // proj GEMM: M=24832 (194x128), N=768 (6x128)
    gemm_proj<<<dim3(194 * 6), 256, 0, stream>>>(attn, pwb, proj_b, out, 6);
}

// Round 17
// 229.916 us; speedup vs baseline: 1.2575x; 1.2575x over previous
//
#include <hip/hip_runtime.h>
#include <cstdint>
#include <cstddef>
#include <cmath>

typedef __attribute__((ext_vector_type(4))) float f32x4;
typedef __attribute__((ext_vector_type(8))) short bf16x8;

typedef const __attribute__((address_space(1))) void* gas_ptr;
typedef __attribute__((address_space(3))) void* las_ptr;

// compiler-native bf16 convert (RNE)
static __device__ __forceinline__ short f2bf(float f) {
    __bf16 h = (__bf16)f;
    return __builtin_bit_cast(short, h);
}

constexpr int MP = 25088;   // 64 * 392 batch-padded rows

// ---------------- merged fp32 -> bf16 conversion (one launch) ----------------
__global__ void cvt_all(const float* __restrict__ x,  const float* __restrict__ qw,
                        const float* __restrict__ pw,
                        short* __restrict__ xb, short* __restrict__ qwb,
                        short* __restrict__ pwb)
{
    constexpr int NX = MP * 768 / 4;
    constexpr int NQ = 2304 * 768 / 4;
    constexpr int NP = 768 * 768 / 4;
    constexpr int NT = NX + NQ + NP;
    int i = blockIdx.x * blockDim.x + threadIdx.x;
    const int stride = gridDim.x * blockDim.x;
    for (; i < NT; i += stride) {
        if (i < NX) {
            const int flat = i * 4;
            const int mp  = flat / 768;
            const int col = flat - mp * 768;
            const int b   = mp / 392;
            const int nn  = mp - b * 392;
            short4 o;
            if (nn < 388) {
                const float4 v = *reinterpret_cast<const float4*>(
                    x + ((size_t)(b * 388 + nn) * 768 + col));
                o.x = f2bf(v.x); o.y = f2bf(v.y); o.z = f2bf(v.z); o.w = f2bf(v.w);
            } else {
                o.x = 0; o.y = 0; o.z = 0; o.w = 0;
            }
            reinterpret_cast<short4*>(xb)[i] = o;
        } else if (i < NX + NQ) {
            const int j = i - NX;
            const float4 v = reinterpret_cast<const float4*>(qw)[j];
            short4 o;
            o.x = f2bf(v.x); o.y = f2bf(v.y); o.z = f2bf(v.z); o.w = f2bf(v.w);
            reinterpret_cast<short4*>(qwb)[j] = o;
        } else {
            const int j = i - NX - NQ;
            const float4 v = reinterpret_cast<const float4*>(pw)[j];
            short4 o;
            o.x = f2bf(v.x); o.y = f2bf(v.y); o.z = f2bf(v.z); o.w = f2bf(v.w);
            reinterpret_cast<short4*>(pwb)[j] = o;
        }
    }
}

// ---------------- QKV GEMM: 256x256, 8 waves (wave tile 128x64), 2-phase ----
// C = A (25088x768) * B^T (2304x768), BK=64, 128KB dbuf LDS, 1 block/CU.
// Rationale: 128x64 wave tiles halve LDS bytes/FLOP vs 64x64 (LDS-BW was
// co-binding the 128^2 engine at ~92% of MFMA time; here ~69%). Loop is the
// r4-verified 2-barrier counted-vmcnt schedule; epilogue is the r10/r11-
// verified clean q/k store + per-wave 64x64 v-transpose (2 passes).
__global__ __launch_bounds__(512, 2) void gemm_qkv256(
    const short* __restrict__ A, const short* __restrict__ Bw,
    const float* __restrict__ bias,
    short* __restrict__ qk, short* __restrict__ vT)
{
    constexpr int K = 768;
    constexpr int KT = 12;
    __shared__ __align__(16) short lds[2][2][256 * 64];   // [buf][op] 128KB

    const int tid  = threadIdx.x;
    const int lane = tid & 63;
    const int wid  = tid >> 6;      // 0..7
    const int lrow = lane & 15;
    const int lgrp = lane >> 4;
    const int wr   = wid >> 2;      // 0..1  (M half)
    const int wc   = wid & 3;       // 0..3  (N quarter)

    // XCD-bijective remap + supertile (98 m-tiles = 7 groups of G=14, 9 n)
    const int nwg = gridDim.x;      // 882
    const int q8  = nwg >> 3, r8 = nwg & 7;
    const int xcd = blockIdx.x & 7, bidx = blockIdx.x >> 3;
    const int wgid = (xcd < r8 ? xcd * (q8 + 1) : r8 * (q8 + 1) + (xcd - r8) * q8) + bidx;
    constexpr int G = 14, SG = G * 9;     // 126; 882 = 7*126
    const int mg  = wgid / SG;
    const int r_  = wgid - mg * SG;
    const int nn_ = r_ / G;
    const int mi  = r_ - nn_ * G;
    const int m0  = (mg * G + mi) * 256;
    const int n0  = nn_ * 256;

    f32x4 acc[8][4];
    #pragma unroll
    for (int i = 0; i < 8; ++i)
        #pragma unroll
        for (int j = 0; j < 4; ++j)
            acc[i][j] = f32x4{0.f, 0.f, 0.f, 0.f};

    // stage one 256x64 tile per op (2048 chunks of 16B each, 4/thread/op)
    auto stage = [&](int kt, int buf) {
        #pragma unroll
        for (int it = 0; it < 4; ++it) {
            const int c   = it * 512 + tid;                  // 0..2047
            const int row = c >> 3;                          // 0..255
            const int scb = ((c & 7) * 16) ^ ((row & 7) << 4);  // inverse swizzle on SOURCE
            const short* ga = A  + (size_t)(m0 + row) * K + kt * 64 + (scb >> 1);
            const short* gb = Bw + (size_t)(n0 + row) * K + kt * 64 + (scb >> 1);
            __builtin_amdgcn_global_load_lds((gas_ptr)ga, (las_ptr)((char*)&lds[buf][0][0] + c * 16), 16, 0, 0);
            __builtin_amdgcn_global_load_lds((gas_ptr)gb, (las_ptr)((char*)&lds[buf][1][0] + c * 16), 16, 0, 0);
        }
    };

    stage(0, 0);   // 8 DMAs/thread in flight

    for (int kt = 0; kt < KT; ++kt) {
        const int cur = kt & 1;
        if (kt + 1 < KT) {
            stage(kt + 1, cur ^ 1);                          // +8 (16 outstanding)
            asm volatile("s_waitcnt vmcnt(8)" ::: "memory"); // tile kt landed
        } else {
            asm volatile("s_waitcnt vmcnt(0)" ::: "memory");
        }
        __builtin_amdgcn_s_barrier();
        __builtin_amdgcn_sched_barrier(0);

        #pragma unroll
        for (int ks = 0; ks < 2; ++ks) {
            bf16x8 af[8], bfv[4];
            #pragma unroll
            for (int i = 0; i < 8; ++i) {
                const int r   = wr * 128 + i * 16 + lrow;
                const int byt = r * 128 + ((ks * 64 + lgrp * 16) ^ ((r & 7) << 4));
                af[i] = *reinterpret_cast<const bf16x8*>((const char*)&lds[cur][0][0] + byt);
            }
            #pragma unroll
            for (int j = 0; j < 4; ++j) {
                const int r   = wc * 64 + j * 16 + lrow;
                const int byt = r * 128 + ((ks * 64 + lgrp * 16) ^ ((r & 7) << 4));
                bfv[j] = *reinterpret_cast<const bf16x8*>((const char*)&lds[cur][1][0] + byt);
            }
            #pragma unroll
            for (int i = 0; i < 8; ++i)
                #pragma unroll
                for (int j = 0; j < 4; ++j)
                    acc[i][j] = __builtin_amdgcn_mfma_f32_16x16x32_bf16(af[i], bfv[j], acc[i][j], 0, 0, 0);
        }

        __builtin_amdgcn_sched_barrier(0);
        __builtin_amdgcn_s_barrier();    // all reads of cur done before overwrite
    }

    // ---------------- epilogue (r10/r11-verified) ----------------
    const int mb = m0 + wr * 128;
    const int nb = n0 + wc * 64;
    if (n0 < 1536) {
        // q/k: coalesced bf16 store into qkb [MP][1536]
        #pragma unroll
        for (int j = 0; j < 4; ++j) {
            const int c  = nb + j * 16 + lrow;
            const float sc = (c < 768) ? 0.18033688011116f : 1.0f;  // 0.125*log2(e) on q
            const float bv = bias[c];
            #pragma unroll
            for (int i = 0; i < 8; ++i) {
                #pragma unroll
                for (int r = 0; r < 4; ++r) {
                    const int m = mb + i * 16 + lgrp * 4 + r;
                    qk[(size_t)m * 1536 + c] = f2bf((acc[i][j][r] + bv) * sc);
                }
            }
        }
    } else {
        // v: per-wave 64x64 in-LDS transpose (2 passes of 64 rows), coalesced vT
        const int h = (nb - 1536) >> 6;
        short* lw = (short*)&lds[0][0][0] + wid * (64 * 80);   // 10KB/wave
        #pragma unroll
        for (int pass = 0; pass < 2; ++pass) {
            if (pass) {
                asm volatile("s_waitcnt lgkmcnt(0)" ::: "memory");
                __builtin_amdgcn_sched_barrier(0);
            }
            #pragma unroll
            for (int j = 0; j < 4; ++j) {
                const int dloc = j * 16 + lrow;
                const float bv = bias[nb + j * 16 + lrow];
                #pragma unroll
                for (int ii = 0; ii < 4; ++ii)
                    #pragma unroll
                    for (int r = 0; r < 4; ++r)
                        lw[dloc * 80 + ii * 16 + lgrp * 4 + r] = f2bf(acc[pass * 4 + ii][j][r] + bv);
            }
            asm volatile("s_waitcnt lgkmcnt(0)" ::: "memory");
            __builtin_amdgcn_sched_barrier(0);
            #pragma unroll
            for (int w = 0; w < 8; ++w) {
                const int d    = w * 8 + (lane >> 3);
                const int nloc = (lane & 7) * 8;
                const bf16x8 val = *reinterpret_cast<const bf16x8*>(lw + d * 80 + nloc);
                const int mchunk = mb + pass * 64 + nloc;      // mult of 8; 392%8==0
                const int b  = mchunk / 392;
                const int nn = mchunk - b * 392;
                short* dst = vT + ((size_t)(b * 12 + h) * 64 + d) * 392 + nn;
                *reinterpret_cast<bf16x8*>(dst) = val;
            }
        }
    }
}

// ---------------- proj GEMM (r14 engine, MODE-1 path) ----------------
__global__ __launch_bounds__(256) void gemm_proj(
    const short* __restrict__ A, const short* __restrict__ Bw,
    const float* __restrict__ bias, float* __restrict__ fo, int NB)
{
    constexpr int K = 768;
    constexpr int KT = 12;
    __shared__ __align__(16) short ldsraw[2 * 128 * 64 * 2];
    short* ldsA = ldsraw;
    short* ldsB = ldsraw + 2 * 128 * 64;

    const int tid  = threadIdx.x;
    const int lane = tid & 63;
    const int wid  = tid >> 6;
    const int lrow = lane & 15;
    const int lgrp = lane >> 4;
    const int wr   = wid >> 1;
    const int wc   = wid & 1;

    const int nwg = gridDim.x;
    const int q8  = nwg >> 3, r8 = nwg & 7;
    const int xcd = blockIdx.x & 7, bidx = blockIdx.x >> 3;
    const int wgid = (xcd < r8 ? xcd * (q8 + 1) : r8 * (q8 + 1) + (xcd - r8) * q8) + bidx;
    const int m0 = (wgid / NB) * 128;
    const int n0 = (wgid % NB) * 128;

    f32x4 acc[4][4];
    #pragma unroll
    for (int i = 0; i < 4; ++i)
        #pragma unroll
        for (int j = 0; j < 4; ++j)
            acc[i][j] = f32x4{0.f, 0.f, 0.f, 0.f};

    auto stage = [&](int kt, int buf) {
        #pragma unroll
        for (int it = 0; it < 4; ++it) {
            const int c   = it * 256 + wid * 64 + lane;
            const int row = c >> 3;
            const int scb = ((c & 7) * 16) ^ ((row & 7) << 4);
            const short* ga = A  + (size_t)(m0 + row) * K + kt * 64 + (scb >> 1);
            const short* gb = Bw + (size_t)(n0 + row) * K + kt * 64 + (scb >> 1);
            __builtin_amdgcn_global_load_lds((gas_ptr)ga, (las_ptr)((char*)(ldsA + buf * 128 * 64) + c * 16), 16, 0, 0);
            __builtin_amdgcn_global_load_lds((gas_ptr)gb, (las_ptr)((char*)(ldsB + buf * 128 * 64) + c * 16), 16, 0, 0);
        }
    };

    stage(0, 0);

    for (int kt = 0; kt < KT; ++kt) {
        const int cur = kt & 1;
        if (kt + 1 < KT) {
            stage(kt + 1, cur ^ 1);
            asm volatile("s_waitcnt vmcnt(8)" ::: "memory");
        } else {
            asm volatile("s_waitcnt vmcnt(0)" ::: "memory");
        }
        __builtin_amdgcn_s_barrier();
        __builtin_amdgcn_sched_barrier(0);

        #pragma unroll
        for (int ks = 0; ks < 2; ++ks) {
            bf16x8 af[4], bfv[4];
            #pragma unroll
            for (int i = 0; i < 4; ++i) {
                const int r   = wr * 64 + i * 16 + lrow;
                const int byt = r * 128 + ((ks * 64 + lgrp * 16) ^ ((r & 7) << 4));
                af[i] = *reinterpret_cast<const bf16x8*>((const char*)(ldsA + cur * 128 * 64) + byt);
            }
            #pragma unroll
            for (int j = 0; j < 4; ++j) {
                const int r   = wc * 64 + j * 16 + lrow;
                const int byt = r * 128 + ((ks * 64 + lgrp * 16) ^ ((r & 7) << 4));
                bfv[j] = *reinterpret_cast<const bf16x8*>((const char*)(ldsB + cur * 128 * 64) + byt);
            }
            #pragma unroll
            for (int i = 0; i < 4; ++i)
                #pragma unroll
                for (int j = 0; j < 4; ++j)
                    acc[i][j] = __builtin_amdgcn_mfma_f32_16x16x32_bf16(af[i], bfv[j], acc[i][j], 0, 0, 0);
        }

        __builtin_amdgcn_sched_barrier(0);
        __builtin_amdgcn_s_barrier();
    }

    const int mb = m0 + wr * 64;
    const int nb = n0 + wc * 64;
    #pragma unroll
    for (int i = 0; i < 4; ++i) {
        #pragma unroll
        for (int r = 0; r < 4; ++r) {
            const int m = mb + i * 16 + lgrp * 4 + r;
            #pragma unroll
            for (int j = 0; j < 4; ++j) {
                const int c = nb + j * 16 + lrow;
                fo[(size_t)m * 768 + c] = acc[i][j][r] + bias[c];
            }
        }
    }
}

// ---------------- flash attention (r14, unchanged) ----------------
constexpr int PSTRB = 128;   // P row stride BYTES (64 keys)

static __device__ __forceinline__ void attn_chunk64(
    int kbeg, int k_len,
    const short* __restrict__ klds, const short* __restrict__ vlds,
    const bf16x8 (&qf)[2], char* __restrict__ my,
    int lrow, int lgrp,
    float& rs, f32x4 (&oacc)[4])
{
    f32x4 sacc[4];
    #pragma unroll
    for (int t = 0; t < 4; ++t) sacc[t] = f32x4{0.f, 0.f, 0.f, 0.f};

    #pragma unroll
    for (int t = 0; t < 4; ++t) {
        const int kl   = t * 16 + lrow;
        const int byt0 = kl * 128 + ((lgrp * 16) ^ ((kl & 7) << 4));
        const int byt1 = kl * 128 + ((64 + lgrp * 16) ^ ((kl & 7) << 4));
        const bf16x8 k0 = *reinterpret_cast<const bf16x8*>((const char*)klds + byt0);
        const bf16x8 k1 = *reinterpret_cast<const bf16x8*>((const char*)klds + byt1);
        // SWAPPED: A = K rows (keys), B = Q rows (q)
        sacc[t] = __builtin_amdgcn_mfma_f32_16x16x32_bf16(k0, qf[0], sacc[t], 0, 0, 0);
        sacc[t] = __builtin_amdgcn_mfma_f32_16x16x32_bf16(k1, qf[1], sacc[t], 0, 0, 0);
    }

    if (kbeg + 64 <= k_len) {          // uniform fast path: no key masking
        #pragma unroll
        for (int t = 0; t < 4; ++t) {
            short4 pk;
            #pragma unroll
            for (int r = 0; r < 4; ++r) {
                const float p = exp2f(sacc[t][r]);
                rs += p;
                ((short*)&pk)[r] = f2bf(p);
            }
            const int byt = lrow * PSTRB + ((t * 32 + lgrp * 8) ^ ((lrow & 7) << 4));
            *reinterpret_cast<short4*>(my + byt) = pk;
        }
    } else {
        #pragma unroll
        for (int t = 0; t < 4; ++t) {
            short4 pk;
            #pragma unroll
            for (int r = 0; r < 4; ++r) {
                const int key = kbeg + t * 16 + lgrp * 4 + r;   // row-indexed
                const float p = (key < k_len) ? exp2f(sacc[t][r]) : 0.f;
                rs += p;
                ((short*)&pk)[r] = f2bf(p);
            }
            const int byt = lrow * PSTRB + ((t * 32 + lgrp * 8) ^ ((lrow & 7) << 4));
            *reinterpret_cast<short4*>(my + byt) = pk;
        }
    }

    #pragma unroll
    for (int ks = 0; ks < 2; ++ks) {
        const bf16x8 pf = *reinterpret_cast<const bf16x8*>(
            my + lrow * PSTRB + ((ks * 64 + lgrp * 16) ^ ((lrow & 7) << 4)));
        #pragma unroll
        for (int dt = 0; dt < 4; ++dt) {
            const int d = dt * 16 + lrow;
            const bf16x8 vf = *reinterpret_cast<const bf16x8*>(
                (const char*)vlds + d * 128 + ((ks * 64 + lgrp * 16) ^ ((d & 7) << 4)));
            oacc[dt] = __builtin_amdgcn_mfma_f32_16x16x32_bf16(pf, vf, oacc[dt], 0, 0, 0);
        }
    }
}

// grid 5376 1-D; temporal-L2 map: 7 q-tiles of one bh consecutive on one XCD.
__global__ __launch_bounds__(256, 4) void attn_flash(
    const short* __restrict__ qkb, const short* __restrict__ vT,
    short* __restrict__ ao)
{
    __shared__ __align__(16) short klds[2][64 * 64];    // 16KB dbuf, swizzled
    __shared__ __align__(16) short vlds[2][64 * 64];    // 16KB dbuf, swizzled
    __shared__ __align__(16) char  plds[4][16 * PSTRB]; // 8KB, swizzled

    const int tid  = threadIdx.x;
    const int lane = tid & 63;
    const int wid  = tid >> 6;
    const int lrow = lane & 15;
    const int lgrp = lane >> 4;

    const int blk = blockIdx.x;
    const int xcd = blk & 7;
    const int i7  = blk >> 3;
    const int bh  = xcd * 96 + i7 / 7;
    const int bx  = i7 % 7;

    int q_start, qend, k_len, nch;
    if (bx < 2) { q_start = bx * 64;             qend = 128; k_len = 128; nch = 2; }
    else        { q_start = 128 + (bx - 2) * 64; qend = 388; k_len = 388; nch = 7; }

    const int q0 = q_start + wid * 16;

    const int b = bh / 12, h = bh - b * 12;
    const short* qbase = qkb + (size_t)b * 392 * 1536 + h * 64;
    const short* kbase = qbase + 768;
    const short* vbase = vT + (size_t)bh * 64 * 392;

    int qrow = q0 + lrow; if (qrow >= qend) qrow = qend - 1;
    bf16x8 qf[2];
    #pragma unroll
    for (int ks = 0; ks < 2; ++ks)
        qf[ks] = *reinterpret_cast<const bf16x8*>(qbase + (size_t)qrow * 1536 + ks * 32 + lgrp * 8);

    float rs = 0.f;
    f32x4 oacc[4];
    #pragma unroll
    for (int dt = 0; dt < 4; ++dt) oacc[dt] = f32x4{0.f, 0.f, 0.f, 0.f};

    char* my = &plds[wid][0];

    auto stage64 = [&](int ch, int buf) {
        const int kbeg = ch * 64;
        #pragma unroll
        for (int it = 0; it < 2; ++it) {
            const int c = it * 256 + tid;            // 0..511
            const int krow = c >> 3;                 // 0..63
            const int scb = ((c & 7) * 16) ^ ((krow & 7) << 4);
            int g = kbeg + krow; if (g > 391) g = 391;   // clamp into batch pad (masked)
            const short* gk = kbase + (size_t)g * 1536 + (scb >> 1);
            __builtin_amdgcn_global_load_lds((gas_ptr)gk, (las_ptr)((char*)&klds[buf][0] + c * 16), 16, 0, 0);
        }
        #pragma unroll
        for (int it = 0; it < 2; ++it) {
            const int c = it * 256 + tid;
            const int vrow = c >> 3;                 // d 0..63
            const int scb = ((c & 7) * 16) ^ ((vrow & 7) << 4);
            const short* gv = vbase + (size_t)vrow * 392 + kbeg + (scb >> 1);  // over-read finite, P==0
            __builtin_amdgcn_global_load_lds((gas_ptr)gv, (las_ptr)((char*)&vlds[buf][0] + c * 16), 16, 0, 0);
        }
    };

    stage64(0, 0);

    for (int ch = 0; ch < nch; ++ch) {
        const int cur = ch & 1;
        if (ch + 1 < nch) {
            stage64(ch + 1, cur ^ 1);                      // next chunk under compute
            asm volatile("s_waitcnt vmcnt(4)" ::: "memory");   // chunk ch landed
        } else {
            asm volatile("s_waitcnt vmcnt(0)" ::: "memory");
        }
        __builtin_amdgcn_s_barrier();
        __builtin_amdgcn_sched_barrier(0);

        attn_chunk64(ch * 64, k_len, &klds[cur][0], &vlds[cur][0],
                     qf, my, lrow, lgrp, rs, oacc);

        __builtin_amdgcn_sched_barrier(0);
        __builtin_amdgcn_s_barrier();   // all reads done before next stage overwrites
    }

    // row-sum lives per-lane for q = lane&15: reduce over the 4 lane-groups
    rs += __shfl_xor(rs, 16, 64);
    rs += __shfl_xor(rs, 32, 64);

    // redistribute: output rows are q = lgrp*4 + r; lanes 0..15 hold rs[q=lane]
    float inv[4];
    #pragma unroll
    for (int r = 0; r < 4; ++r) inv[r] = 1.0f / __shfl(rs, lgrp * 4 + r, 64);

    #pragma unroll
    for (int r = 0; r < 4; ++r) {
        const int qn = q0 + lgrp * 4 + r;
        if (qn < qend) {
            #pragma unroll
            for (int dt = 0; dt < 4; ++dt)
                ao[((size_t)b * 388 + qn) * 768 + h * 64 + dt * 16 + lrow] =
                    f2bf(oacc[dt][r] * inv[r]);
        }
    }
}

extern "C" void kernel_launch(void* const* d_in, const int* in_sizes, int n_in,
                              void* d_out, int out_size, void* d_ws, size_t ws_size,
                              hipStream_t stream) {
    (void)in_sizes; (void)n_in; (void)out_size; (void)ws_size;
    const float* x      = (const float*)d_in[0];
    const float* qkv_w  = (const float*)d_in[1];
    const float* qkv_b  = (const float*)d_in[2];
    const float* proj_w = (const float*)d_in[3];
    const float* proj_b = (const float*)d_in[4];
    float* out = (float*)d_out;

    char* ws = (char*)d_ws;
    short* xb   = (short*)(ws);                       // [25088][768] bf16 (padded x)
    short* attn = (short*)(ws);                       //   alias: xb dead after QKV GEMM
    short* qkb  = (short*)(ws + 38535168);            // [25088][1536] bf16 (q|k)
    short* vTb  = (short*)(ws + 115605504);           // [768][64][392] bf16
    short* qwb  = (short*)(ws + 154140672);           // 2304x768 bf16 (V tail over-reads land here)
    short* pwb  = (short*)(ws + 157679616);           // 768x768 bf16

    cvt_all<<<2048, 256, 0, stream>>>(x, qkv_w, proj_w, xb, qwb, pwb);

    // QKV GEMM: M'=25088 (98x256), N=2304 (9x256), 8-wave 2-phase
    gemm_qkv256<<<dim3(98 * 9), 512, 0, stream>>>(xb, qwb, qkv_b, qkb, vTb);

    attn_flash<<<dim3(5376), 256, 0, stream>>>(qkb, vTb, attn);

    // proj GEMM: M=24832 (194x128), N=768 (6x128)
    gemm_proj<<<dim3(194 * 6), 256, 0, stream>>>(attn, pwb, proj_b, out, 6);
}